// Round 1
// baseline (105.154 us; speedup 1.0000x reference)
//
#include <hip/hip_runtime.h>
#include <math.h>

// RWKV WKV forward, chunked-scan formulation.
// State triple (aa, bb, pp) represents A = e^pp * aa, B = e^pp * bb.
// Underlying linear recurrence: A' = e^w A + e^{k_t} v_t ; B' = e^w B + e^{k_t}.
// Chunk of length L: A_out = e^{wL} A_in + A_local  -> associative combine.

#define NEG_INF (-1e38f)

// Pass 1: per-(b,c,chunk) local state from zero init.
__global__ void wkv_chunk_state(const float* __restrict__ w,
                                const float* __restrict__ k,
                                const float* __restrict__ v,
                                float* __restrict__ sa,
                                float* __restrict__ sb,
                                float* __restrict__ sp,
                                int B, int T, int C, int L, int NC) {
    int tid = blockIdx.x * blockDim.x + threadIdx.x;
    int BC = B * C;
    if (tid >= BC * NC) return;
    int j  = tid / BC;          // chunk index
    int bc = tid - j * BC;      // channel (b*C + c); consecutive lanes -> consecutive c (coalesced)
    int b  = bc / C;
    int c  = bc - b * C;

    float wc = w[c];
    const float* kp = k + ((size_t)b * T + (size_t)j * L) * C + c;
    const float* vp = v + ((size_t)b * T + (size_t)j * L) * C + c;

    float aa = 0.f, bb = 0.f, pp = NEG_INF;
    #pragma unroll 4
    for (int t = 0; t < L; ++t) {
        float kt = *kp; kp += C;
        float vt = *vp; vp += C;
        float ww = wc + pp;
        float p  = fmaxf(ww, kt);
        float e1 = __expf(ww - p);
        float e2 = __expf(kt - p);
        aa = e1 * aa + e2 * vt;
        bb = e1 * bb + e2;
        pp = p;
    }
    sa[tid] = aa;
    sb[tid] = bb;
    sp[tid] = pp;
}

// Pass 2: sequential prefix over chunks per channel. Overwrites the summary
// arrays in place with the carry-in (state before each chunk).
__global__ void wkv_prefix(const float* __restrict__ w,
                           float* __restrict__ sa,
                           float* __restrict__ sb,
                           float* __restrict__ sp,
                           int B, int C, int L, int NC) {
    int bc = blockIdx.x * blockDim.x + threadIdx.x;
    int BC = B * C;
    if (bc >= BC) return;
    int c = bc % C;
    float wL = w[c] * (float)L;

    float aa = 0.f, bb = 0.f, pp = NEG_INF;
    for (int j = 0; j < NC; ++j) {
        int idx = j * BC + bc;
        float la = sa[idx];
        float lb = sb[idx];
        float lp = sp[idx];
        // store carry-in for chunk j
        sa[idx] = aa;
        sb[idx] = bb;
        sp[idx] = pp;
        // running = decay(running, wL) + local
        float ppd = pp + wL;              // -1e38 absorbs wL harmlessly
        float p   = fmaxf(ppd, lp);
        float e1  = __expf(ppd - p);      // exp(-huge) -> 0 for first chunk
        float e2  = __expf(lp - p);
        aa = e1 * aa + e2 * la;
        bb = e1 * bb + e2 * lb;
        pp = p;
    }
}

// Pass 3: recompute within chunk from carry-in, emit y (exact reference step).
__global__ void wkv_out(const float* __restrict__ w,
                        const float* __restrict__ u,
                        const float* __restrict__ k,
                        const float* __restrict__ v,
                        const float* __restrict__ sa,
                        const float* __restrict__ sb,
                        const float* __restrict__ sp,
                        float* __restrict__ y,
                        int B, int T, int C, int L, int NC) {
    int tid = blockIdx.x * blockDim.x + threadIdx.x;
    int BC = B * C;
    if (tid >= BC * NC) return;
    int j  = tid / BC;
    int bc = tid - j * BC;
    int b  = bc / C;
    int c  = bc - b * C;

    float wc = w[c];
    float uc = u[c];
    size_t base = ((size_t)b * T + (size_t)j * L) * C + c;
    const float* kp = k + base;
    const float* vp = v + base;
    float*       yp = y + base;

    float aa = sa[tid], bb = sb[tid], pp = sp[tid];

    #pragma unroll 4
    for (int t = 0; t < L; ++t) {
        float kt = *kp; kp += C;
        float vt = *vp; vp += C;
        // output (time-first boost u), state BEFORE this step
        float ww = uc + kt;
        float p  = fmaxf(pp, ww);
        float e1 = __expf(pp - p);
        float e2 = __expf(ww - p);
        float num = e1 * aa + e2 * vt;
        float den = e1 * bb + e2;
        *yp = __fdividef(num, den); yp += C;
        // state update (decay w)
        float ww2 = wc + pp;
        float p2  = fmaxf(ww2, kt);
        float e1b = __expf(ww2 - p2);
        float e2b = __expf(kt - p2);
        aa = e1b * aa + e2b * vt;
        bb = e1b * bb + e2b;
        pp = p2;
    }
}

extern "C" void kernel_launch(void* const* d_in, const int* in_sizes, int n_in,
                              void* d_out, int out_size, void* d_ws, size_t ws_size,
                              hipStream_t stream) {
    // inputs: 0=B(scalar dev ptr) 1=T 2=C 3=w 4=u 5=k 6=v
    const float* w = (const float*)d_in[3];
    const float* u = (const float*)d_in[4];
    const float* k = (const float*)d_in[5];
    const float* v = (const float*)d_in[6];
    float* y = (float*)d_out;

    const int C  = in_sizes[3];            // 768
    const int BT = in_sizes[5] / C;        // B*T = 32768
    const int T  = 4096;                   // fixed problem instance
    const int B  = BT / T;                 // 8

    // pick NC (power of two) that fits workspace: need 3*B*C*NC floats
    int NC = 64;
    while (NC > 1 && ((size_t)3 * B * C * NC * sizeof(float) > ws_size || (T % NC) != 0))
        NC >>= 1;
    const int L = T / NC;

    const int BC    = B * C;
    const int total = BC * NC;
    float* sa = (float*)d_ws;
    float* sb = sa + total;
    float* sp = sb + total;

    const int blk = 256;
    wkv_chunk_state<<<(total + blk - 1) / blk, blk, 0, stream>>>(w, k, v, sa, sb, sp, B, T, C, L, NC);
    wkv_prefix<<<(BC + blk - 1) / blk, blk, 0, stream>>>(w, sa, sb, sp, B, C, L, NC);
    wkv_out<<<(total + blk - 1) / blk, blk, 0, stream>>>(w, u, k, v, sa, sb, sp, y, B, T, C, L, NC);
}